// Round 11
// baseline (146.043 us; speedup 1.0000x reference)
//
#include <hip/hip_runtime.h>
#include <hip/hip_bf16.h>

#define B_ 4
#define C_IN 128
#define C_OUT 256
#define N_IN 40962
#define N_OUT 10242
#define EPS_ 1e-5f
#define CNT_ ((float)(B_ * N_OUT))

typedef __attribute__((ext_vector_type(8))) short bf16x8;
typedef __attribute__((ext_vector_type(4))) float f32x4;

__device__ __forceinline__ float bf2f(unsigned short u) {
    union { unsigned int i; float f; } c;
    c.i = ((unsigned int)u) << 16;
    return c.f;
}
__device__ __forceinline__ unsigned short f2bf(float f) {
    union { float f; unsigned int i; } c;
    c.f = f;
    unsigned int r = c.i + 0x7FFFu + ((c.i >> 16) & 1u);  // RNE
    return (unsigned short)(r >> 16);
}

// ---------------------------------------------------------------------------
// K1: transpose x[b][k][i] (f32) -> xT[b][i][k] (bf16); trailing blocks do
//     the W f32->bf16 conversion; first wconv block also zeroes the counters.
// ---------------------------------------------------------------------------
#define IBLK 64
#define NB_I ((N_IN + IBLK - 1) / IBLK)   // 641
#define WCONV_BLKS ((C_OUT * C_IN) / 256) // 128

__global__ __launch_bounds__(256) void k_transpose(const float* __restrict__ x,
                                                   unsigned short* __restrict__ xT,
                                                   const float* __restrict__ W,
                                                   unsigned short* __restrict__ Wb,
                                                   unsigned int* __restrict__ cnt) {
    if (blockIdx.x >= B_ * NB_I) {
        if (blockIdx.x == B_ * NB_I && threadIdx.x < 2) cnt[threadIdx.x] = 0;
        int i = (blockIdx.x - B_ * NB_I) * 256 + threadIdx.x;
        Wb[i] = f2bf(W[i]);
        return;
    }
    __shared__ float tile[IBLK][C_IN + 1];
    int b  = blockIdx.x / NB_I;
    int ib = blockIdx.x % NB_I;
    int i0 = ib * IBLK;
    int t = threadIdx.x;
    int lane = t & 63;
    int q = t >> 6;

    const float* xb = x + (size_t)b * C_IN * N_IN;
    int i = i0 + lane;
    if (i < N_IN) {
#pragma unroll
        for (int p = 0; p < 32; p++) {
            int k = p * 4 + q;
            tile[lane][k] = xb[(size_t)k * N_IN + i];
        }
    }
    __syncthreads();

    unsigned short* xTb = xT + (size_t)b * N_IN * C_IN;
#pragma unroll
    for (int p = 0; p < 16; p++) {
        int il = p * 4 + q;
        int gi = i0 + il;
        if (gi < N_IN) {
            int k2 = lane * 2;
            float a = tile[il][k2];
            float c = tile[il][k2 + 1];
            unsigned int pk = (unsigned int)f2bf(a) | ((unsigned int)f2bf(c) << 16);
            *reinterpret_cast<unsigned int*>(xTb + (size_t)gi * C_IN + k2) = pk;
        }
    }
}

// ---------------------------------------------------------------------------
// K2: gather-mean: g[b][n][k] = mean_j xT[b][idx[7n+j]][k]  (bf16 out)
// ---------------------------------------------------------------------------
#define GNB 16
#define NB_G ((N_OUT + GNB - 1) / GNB)  // 641

__global__ __launch_bounds__(256) void k_gather(const unsigned short* __restrict__ xT,
                                                const int* __restrict__ idx,
                                                unsigned short* __restrict__ g) {
    int b  = blockIdx.x / NB_G;
    int nb = blockIdx.x % NB_G;
    int t = threadIdx.x;
    int n = nb * GNB + (t >> 4);
    int c = t & 15;
    if (n >= N_OUT) return;

    const unsigned short* xTb = xT + (size_t)b * N_IN * C_IN;
    const int* ip = idx + 7 * n;
    float s[8];
#pragma unroll
    for (int e = 0; e < 8; e++) s[e] = 0.f;
#pragma unroll
    for (int j = 0; j < 7; j++) {
        int id = ip[j];
        bf16x8 v = *reinterpret_cast<const bf16x8*>(xTb + (size_t)id * C_IN + c * 8);
#pragma unroll
        for (int e = 0; e < 8; e++) s[e] += bf2f((unsigned short)v[e]);
    }
    const float inv7 = 1.0f / 7.0f;
    bf16x8 r;
#pragma unroll
    for (int e = 0; e < 8; e++) r[e] = (short)f2bf(s[e] * inv7);
    *reinterpret_cast<bf16x8*>(g + ((size_t)b * N_OUT + n) * C_IN + c * 8) = r;
}

// ---------------------------------------------------------------------------
// K3 (fused, manual grid barrier): phase A GEMM->psum; blocks 0..63 reduce ->
// ss; all blocks recompute GEMM and normalize+store.
// 324 blocks @ __launch_bounds__(256,2): capacity 512 >= 324 -> all resident,
// spin cannot deadlock. Cross-XCD visibility via __threadfence + agent-scope
// atomics (Guideline 16).
// ---------------------------------------------------------------------------
#define NT2 128
#define NB_N2 ((N_OUT + NT2 - 1) / NT2)  // 81
#define NBLK_GS (B_ * NB_N2)             // 324

__global__ __launch_bounds__(256, 2) void k_fused_gemm(const unsigned short* __restrict__ g,
                                                       const unsigned short* __restrict__ Wb,
                                                       const float* __restrict__ bias,
                                                       const float* __restrict__ gamma,
                                                       const float* __restrict__ beta,
                                                       float* __restrict__ psum,
                                                       float* __restrict__ ss,
                                                       unsigned int* __restrict__ cnt,
                                                       float* __restrict__ out) {
    __shared__ float red[2][C_OUT];
    __shared__ float lds_a[C_OUT];
    __shared__ float lds_s[C_OUT];

    int bid = blockIdx.x;
    int b  = bid / NB_N2;
    int nb = bid % NB_N2;
    int t = threadIdx.x;
    int w = t >> 6, l = t & 63, lr = l & 15, lg = l >> 4;
    int wbase = w * 64;

    bf16x8 afrag[4][4];
#pragma unroll
    for (int mt = 0; mt < 4; mt++)
#pragma unroll
        for (int ks = 0; ks < 4; ks++)
            afrag[mt][ks] = *reinterpret_cast<const bf16x8*>(
                Wb + (size_t)(wbase + mt * 16 + lr) * C_IN + ks * 32 + lg * 8);

    const unsigned short* gb = g + (size_t)b * N_OUT * C_IN;

    // ---------------- Phase A: stats GEMM (z = Wg, bias-free) ----------------
    float ps1[16], ps2[16];
#pragma unroll
    for (int m = 0; m < 16; m++) { ps1[m] = 0.f; ps2[m] = 0.f; }

    for (int h = 0; h < 2; h++) {
        int n0 = nb * NT2 + h * 64;
        f32x4 acc[4][4];
#pragma unroll
        for (int mt = 0; mt < 4; mt++)
#pragma unroll
            for (int nt = 0; nt < 4; nt++) acc[mt][nt] = (f32x4)(0.0f);
#pragma unroll
        for (int nt = 0; nt < 4; nt++) {
            int n = n0 + nt * 16 + lr;
            const unsigned short* gr = gb + (size_t)((n < N_OUT) ? n : 0) * C_IN;
#pragma unroll
            for (int ks = 0; ks < 4; ks++) {
                bf16x8 bfr = *reinterpret_cast<const bf16x8*>(gr + ks * 32 + lg * 8);
#pragma unroll
                for (int mt = 0; mt < 4; mt++)
                    acc[mt][nt] = __builtin_amdgcn_mfma_f32_16x16x32_bf16(afrag[mt][ks], bfr,
                                                                         acc[mt][nt], 0, 0, 0);
            }
        }
#pragma unroll
        for (int mt = 0; mt < 4; mt++)
#pragma unroll
            for (int j = 0; j < 4; j++)
#pragma unroll
                for (int nt = 0; nt < 4; nt++) {
                    int n = n0 + nt * 16 + lr;
                    if (n < N_OUT) {
                        float v = acc[mt][nt][j];
                        ps1[mt * 4 + j] += v;
                        ps2[mt * 4 + j] += v * v;
                    }
                }
    }

#pragma unroll
    for (int m = 0; m < 16; m++) {
        float a = ps1[m], cc = ps2[m];
#pragma unroll
        for (int d = 1; d < 16; d <<= 1) {
            a  += __shfl_xor(a, d, 64);
            cc += __shfl_xor(cc, d, 64);
        }
        if (lr == 0) {
            int mt = m >> 2, j = m & 3;
            int o = wbase + mt * 16 + lg * 4 + j;
            red[0][o] = a;
            red[1][o] = cc;
        }
    }
    __syncthreads();
    {
        float* pb = psum + (size_t)bid * 2 * C_OUT;
        pb[t] = red[0][t];
        pb[C_OUT + t] = red[1][t];
    }
    __threadfence();
    __syncthreads();
    if (t == 0)
        __hip_atomic_fetch_add(&cnt[0], 1u, __ATOMIC_RELEASE, __HIP_MEMORY_SCOPE_AGENT);

    // ---------------- Reducers: blocks 0..63 -> ss ----------------
    if (bid < 64) {
        if (t == 0) {
            while (__hip_atomic_load(&cnt[0], __ATOMIC_ACQUIRE, __HIP_MEMORY_SCOPE_AGENT)
                   < (unsigned)NBLK_GS)
                __builtin_amdgcn_s_sleep(8);
        }
        __syncthreads();
        int o = bid * 4 + w;
        float s1 = 0.f, s2 = 0.f;
        for (int i = l; i < NBLK_GS; i += 64) {
            const float* pb = psum + (size_t)i * 2 * C_OUT;
            s1 += pb[o];
            s2 += pb[C_OUT + o];
        }
#pragma unroll
        for (int d = 1; d < 64; d <<= 1) {
            s1 += __shfl_xor(s1, d, 64);
            s2 += __shfl_xor(s2, d, 64);
        }
        if (l == 0) {
            float mz = s1 / CNT_;
            float var = s2 / CNT_ - mz * mz;   // var(y) == var(z)
            float a = gamma[o] * rsqrtf(var + EPS_);
            ss[o] = a;
            ss[C_OUT + o] = beta[o] - a * mz;  // bias cancels in (y - mean)
        }
        __threadfence();
        __syncthreads();
        if (t == 0)
            __hip_atomic_fetch_add(&cnt[1], 1u, __ATOMIC_RELEASE, __HIP_MEMORY_SCOPE_AGENT);
    }

    // ---------------- Phase B: recompute z, normalize, store ----------------
    float* ob = out + (size_t)b * C_OUT * N_OUT;
    bool have_ss = false;
    for (int h = 0; h < 2; h++) {
        int n0 = nb * NT2 + h * 64;
        f32x4 acc[4][4];
#pragma unroll
        for (int mt = 0; mt < 4; mt++)
#pragma unroll
            for (int nt = 0; nt < 4; nt++) acc[mt][nt] = (f32x4)(0.0f);
#pragma unroll
        for (int nt = 0; nt < 4; nt++) {
            int n = n0 + nt * 16 + lr;
            const unsigned short* gr = gb + (size_t)((n < N_OUT) ? n : 0) * C_IN;
#pragma unroll
            for (int ks = 0; ks < 4; ks++) {
                bf16x8 bfr = *reinterpret_cast<const bf16x8*>(gr + ks * 32 + lg * 8);
#pragma unroll
                for (int mt = 0; mt < 4; mt++)
                    acc[mt][nt] = __builtin_amdgcn_mfma_f32_16x16x32_bf16(afrag[mt][ks], bfr,
                                                                         acc[mt][nt], 0, 0, 0);
            }
        }

        if (!have_ss) {  // MFMA above overlapped the reducers' work; wait now
            if (t == 0) {
                while (__hip_atomic_load(&cnt[1], __ATOMIC_ACQUIRE, __HIP_MEMORY_SCOPE_AGENT)
                       < 64u)
                    __builtin_amdgcn_s_sleep(8);
            }
            __syncthreads();
            lds_a[t] = ss[t];
            lds_s[t] = ss[C_OUT + t];
            __syncthreads();
            have_ss = true;
        }

#pragma unroll
        for (int mt = 0; mt < 4; mt++) {
#pragma unroll
            for (int j = 0; j < 4; j++) {
                int o = wbase + mt * 16 + lg * 4 + j;
                float a = lds_a[o];
                float s = lds_s[o];
#pragma unroll
                for (int nt = 0; nt < 4; nt++) {
                    int n = n0 + nt * 16 + lr;
                    if (n < N_OUT) ob[(size_t)o * N_OUT + n] = a * acc[mt][nt][j] + s;
                }
            }
        }
    }
}

// ---------------------------------------------------------------------------
extern "C" void kernel_launch(void* const* d_in, const int* in_sizes, int n_in,
                              void* d_out, int out_size, void* d_ws, size_t ws_size,
                              hipStream_t stream) {
    const float* x     = (const float*)d_in[0];
    const int*   idx   = (const int*)d_in[1];
    const float* W     = (const float*)d_in[2];
    const float* bias  = (const float*)d_in[3];
    const float* gamma = (const float*)d_in[4];
    const float* beta  = (const float*)d_in[5];
    float* out = (float*)d_out;

    const size_t xt_bytes = (size_t)B_ * N_IN * C_IN * sizeof(unsigned short);   // 41,945,088
    const size_t g_bytes  = (size_t)B_ * N_OUT * C_IN * sizeof(unsigned short);  // 10,487,808
    const size_t wb_bytes = (size_t)C_OUT * C_IN * sizeof(unsigned short);       // 65,536
    unsigned short* xT = (unsigned short*)d_ws;
    unsigned short* gg = (unsigned short*)((char*)d_ws + xt_bytes);
    unsigned short* Wb = (unsigned short*)((char*)d_ws + xt_bytes + g_bytes);
    float* psum = (float*)((char*)d_ws + xt_bytes + g_bytes + wb_bytes);         // 324*512*4 = 663 KB
    float* ss   = psum + (size_t)NBLK_GS * 2 * C_OUT;
    unsigned int* cnt = (unsigned int*)(ss + 2 * C_OUT);

    k_transpose<<<B_ * NB_I + WCONV_BLKS, 256, 0, stream>>>(x, xT, W, Wb, cnt);
    k_gather<<<B_ * NB_G, 256, 0, stream>>>(xT, idx, gg);
    k_fused_gemm<<<NBLK_GS, 256, 0, stream>>>(gg, Wb, bias, gamma, beta, psum, ss, cnt, out);
}

// Round 13
// 122.232 us; speedup vs baseline: 1.1948x; 1.1948x over previous
//
#include <hip/hip_runtime.h>
#include <hip/hip_bf16.h>

#define B_ 4
#define C_IN 128
#define C_OUT 256
#define N_IN 40962
#define N_OUT 10242
#define EPS_ 1e-5f
#define CNT_ ((float)(B_ * N_OUT))

typedef __attribute__((ext_vector_type(8))) short bf16x8;
typedef __attribute__((ext_vector_type(4))) float f32x4;

__device__ __forceinline__ float bf2f(unsigned short u) {
    union { unsigned int i; float f; } c;
    c.i = ((unsigned int)u) << 16;
    return c.f;
}
__device__ __forceinline__ unsigned short f2bf(float f) {
    union { float f; unsigned int i; } c;
    c.f = f;
    unsigned int r = c.i + 0x7FFFu + ((c.i >> 16) & 1u);  // RNE
    return (unsigned short)(r >> 16);
}

// ---------------------------------------------------------------------------
// K1: transpose x[b][k][i] (f32) -> xT[b][i][k] (bf16); trailing blocks do
//     the W f32->bf16 conversion; first wconv block zeroes the counter.
// ---------------------------------------------------------------------------
#define IBLK 64
#define NB_I ((N_IN + IBLK - 1) / IBLK)   // 641
#define WCONV_BLKS ((C_OUT * C_IN) / 256) // 128

__global__ __launch_bounds__(256) void k_transpose(const float* __restrict__ x,
                                                   unsigned short* __restrict__ xT,
                                                   const float* __restrict__ W,
                                                   unsigned short* __restrict__ Wb,
                                                   unsigned int* __restrict__ cnt) {
    if (blockIdx.x >= B_ * NB_I) {
        if (blockIdx.x == B_ * NB_I && threadIdx.x == 0) cnt[0] = 0;
        int i = (blockIdx.x - B_ * NB_I) * 256 + threadIdx.x;
        Wb[i] = f2bf(W[i]);
        return;
    }
    __shared__ float tile[IBLK][C_IN + 1];
    int b  = blockIdx.x / NB_I;
    int ib = blockIdx.x % NB_I;
    int i0 = ib * IBLK;
    int t = threadIdx.x;
    int lane = t & 63;
    int q = t >> 6;

    const float* xb = x + (size_t)b * C_IN * N_IN;
    int i = i0 + lane;
    if (i < N_IN) {
#pragma unroll
        for (int p = 0; p < 32; p++) {
            int k = p * 4 + q;
            tile[lane][k] = xb[(size_t)k * N_IN + i];
        }
    }
    __syncthreads();

    unsigned short* xTb = xT + (size_t)b * N_IN * C_IN;
#pragma unroll
    for (int p = 0; p < 16; p++) {
        int il = p * 4 + q;
        int gi = i0 + il;
        if (gi < N_IN) {
            int k2 = lane * 2;
            float a = tile[il][k2];
            float c = tile[il][k2 + 1];
            unsigned int pk = (unsigned int)f2bf(a) | ((unsigned int)f2bf(c) << 16);
            *reinterpret_cast<unsigned int*>(xTb + (size_t)gi * C_IN + k2) = pk;
        }
    }
}

// ---------------------------------------------------------------------------
// K2: gather-mean: g[b][n][k] = mean_j xT[b][idx[7n+j]][k]  (bf16 out)
// 16 threads per n; 2564 blocks for max TLP on the random L3 reads.
// ---------------------------------------------------------------------------
#define GNB 16
#define NB_G ((N_OUT + GNB - 1) / GNB)  // 641

__global__ __launch_bounds__(256) void k_gather(const unsigned short* __restrict__ xT,
                                                const int* __restrict__ idx,
                                                unsigned short* __restrict__ g) {
    int b  = blockIdx.x / NB_G;
    int nb = blockIdx.x % NB_G;
    int t = threadIdx.x;
    int n = nb * GNB + (t >> 4);
    int c = t & 15;
    if (n >= N_OUT) return;

    const unsigned short* xTb = xT + (size_t)b * N_IN * C_IN;
    const int* ip = idx + 7 * n;
    float s[8];
#pragma unroll
    for (int e = 0; e < 8; e++) s[e] = 0.f;
#pragma unroll
    for (int j = 0; j < 7; j++) {
        int id = ip[j];
        bf16x8 v = *reinterpret_cast<const bf16x8*>(xTb + (size_t)id * C_IN + c * 8);
#pragma unroll
        for (int e = 0; e < 8; e++) s[e] += bf2f((unsigned short)v[e]);
    }
    const float inv7 = 1.0f / 7.0f;
    bf16x8 r;
#pragma unroll
    for (int e = 0; e < 8; e++) r[e] = (short)f2bf(s[e] * inv7);
    *reinterpret_cast<bf16x8*>(g + ((size_t)b * N_OUT + n) * C_IN + c * 8) = r;
}

// ---------------------------------------------------------------------------
// GEMM tiling: 128-n tile per block processed as 2x 64-n halves reusing the
// same acc registers (afrag/Wb loaded once per block, epilogue amortized).
// ---------------------------------------------------------------------------
#define NT2 128
#define NB_N2 ((N_OUT + NT2 - 1) / NT2)  // 81
#define NBLK_GS (B_ * NB_N2)             // 324

// K3: GEMM -> per-block per-channel partials of z=Wg; the LAST finishing block
// (producer-exit pattern: no spinning, deadlock-impossible) reduces psum -> ss.
__global__ __launch_bounds__(256, 2) void k_stats_gemm(const unsigned short* __restrict__ g,
                                                       const unsigned short* __restrict__ Wb,
                                                       const float* __restrict__ gamma,
                                                       const float* __restrict__ beta,
                                                       float* __restrict__ psum,
                                                       float* __restrict__ ss,
                                                       unsigned int* __restrict__ cnt) {
    int bid = blockIdx.x;
    int b  = bid / NB_N2;
    int nb = bid % NB_N2;
    int t = threadIdx.x;
    int w = t >> 6, l = t & 63, lr = l & 15, lg = l >> 4;
    int wbase = w * 64;

    bf16x8 afrag[4][4];
#pragma unroll
    for (int mt = 0; mt < 4; mt++)
#pragma unroll
        for (int ks = 0; ks < 4; ks++)
            afrag[mt][ks] = *reinterpret_cast<const bf16x8*>(
                Wb + (size_t)(wbase + mt * 16 + lr) * C_IN + ks * 32 + lg * 8);

    const unsigned short* gb = g + (size_t)b * N_OUT * C_IN;
    float ps1[16], ps2[16];
#pragma unroll
    for (int m = 0; m < 16; m++) { ps1[m] = 0.f; ps2[m] = 0.f; }

    for (int h = 0; h < 2; h++) {
        int n0 = nb * NT2 + h * 64;
        f32x4 acc[4][4];
#pragma unroll
        for (int mt = 0; mt < 4; mt++)
#pragma unroll
            for (int nt = 0; nt < 4; nt++) acc[mt][nt] = (f32x4)(0.0f);

#pragma unroll
        for (int nt = 0; nt < 4; nt++) {
            int n = n0 + nt * 16 + lr;
            const unsigned short* gr = gb + (size_t)((n < N_OUT) ? n : 0) * C_IN;
#pragma unroll
            for (int ks = 0; ks < 4; ks++) {
                bf16x8 bfr = *reinterpret_cast<const bf16x8*>(gr + ks * 32 + lg * 8);
#pragma unroll
                for (int mt = 0; mt < 4; mt++)
                    acc[mt][nt] = __builtin_amdgcn_mfma_f32_16x16x32_bf16(afrag[mt][ks], bfr,
                                                                         acc[mt][nt], 0, 0, 0);
            }
        }
#pragma unroll
        for (int mt = 0; mt < 4; mt++)
#pragma unroll
            for (int j = 0; j < 4; j++)
#pragma unroll
                for (int nt = 0; nt < 4; nt++) {
                    int n = n0 + nt * 16 + lr;
                    if (n < N_OUT) {
                        float v = acc[mt][nt][j];
                        ps1[mt * 4 + j] += v;
                        ps2[mt * 4 + j] += v * v;
                    }
                }
    }

    __shared__ float red[2][C_OUT];
#pragma unroll
    for (int m = 0; m < 16; m++) {
        float a = ps1[m], cc = ps2[m];
#pragma unroll
        for (int d = 1; d < 16; d <<= 1) {
            a  += __shfl_xor(a, d, 64);
            cc += __shfl_xor(cc, d, 64);
        }
        if (lr == 0) {
            int mt = m >> 2, j = m & 3;
            int o = wbase + mt * 16 + lg * 4 + j;
            red[0][o] = a;
            red[1][o] = cc;
        }
    }
    __syncthreads();
    {
        float* pb = psum + (size_t)bid * 2 * C_OUT;
        pb[t] = red[0][t];
        pb[C_OUT + t] = red[1][t];
    }

    // --- last-block-reduces: release psum, count; only the last block works ---
    __threadfence();
    __syncthreads();
    __shared__ unsigned int lastflag;
    if (t == 0) {
        unsigned int prev = __hip_atomic_fetch_add(&cnt[0], 1u, __ATOMIC_ACQ_REL,
                                                   __HIP_MEMORY_SCOPE_AGENT);
        lastflag = (prev == (unsigned)(NBLK_GS - 1));
    }
    __syncthreads();
    if (lastflag) {
        __threadfence();  // acquire: all psum writes visible (released above)
        float s1 = 0.f, s2 = 0.f;
        for (int i = 0; i < NBLK_GS; i++) {
            const float* pb2 = psum + (size_t)i * 2 * C_OUT;
            s1 += pb2[t];
            s2 += pb2[C_OUT + t];
        }
        float mz = s1 / CNT_;
        float var = s2 / CNT_ - mz * mz;     // var(y) == var(z); bias cancels
        float a = gamma[t] * rsqrtf(var + EPS_);
        ss[t] = a;
        ss[C_OUT + t] = beta[t] - a * mz;    // out = a*z + (beta - a*mz)
    }
}

// ---------------------------------------------------------------------------
// K4: GEMM (z = Wg) + out = a*z + shift. Same 2-half outer loop.
// ---------------------------------------------------------------------------
__global__ __launch_bounds__(256, 2) void k_final_gemm(const unsigned short* __restrict__ g,
                                                       const unsigned short* __restrict__ Wb,
                                                       const float* __restrict__ ss,
                                                       float* __restrict__ out) {
    int bid = blockIdx.x;
    int b  = bid / NB_N2;
    int nb = bid % NB_N2;
    int t = threadIdx.x;
    int w = t >> 6, l = t & 63, lr = l & 15, lg = l >> 4;
    int wbase = w * 64;

    bf16x8 afrag[4][4];
#pragma unroll
    for (int mt = 0; mt < 4; mt++)
#pragma unroll
        for (int ks = 0; ks < 4; ks++)
            afrag[mt][ks] = *reinterpret_cast<const bf16x8*>(
                Wb + (size_t)(wbase + mt * 16 + lr) * C_IN + ks * 32 + lg * 8);

    float sa[16], sh[16];
#pragma unroll
    for (int mt = 0; mt < 4; mt++)
#pragma unroll
        for (int j = 0; j < 4; j++) {
            int o = wbase + mt * 16 + lg * 4 + j;
            sa[mt * 4 + j] = ss[o];
            sh[mt * 4 + j] = ss[C_OUT + o];
        }

    const unsigned short* gb = g + (size_t)b * N_OUT * C_IN;
    float* ob = out + (size_t)b * C_OUT * N_OUT;

    for (int h = 0; h < 2; h++) {
        int n0 = nb * NT2 + h * 64;
        f32x4 acc[4][4];
#pragma unroll
        for (int mt = 0; mt < 4; mt++)
#pragma unroll
            for (int nt = 0; nt < 4; nt++) acc[mt][nt] = (f32x4)(0.0f);

#pragma unroll
        for (int nt = 0; nt < 4; nt++) {
            int n = n0 + nt * 16 + lr;
            const unsigned short* gr = gb + (size_t)((n < N_OUT) ? n : 0) * C_IN;
#pragma unroll
            for (int ks = 0; ks < 4; ks++) {
                bf16x8 bfr = *reinterpret_cast<const bf16x8*>(gr + ks * 32 + lg * 8);
#pragma unroll
                for (int mt = 0; mt < 4; mt++)
                    acc[mt][nt] = __builtin_amdgcn_mfma_f32_16x16x32_bf16(afrag[mt][ks], bfr,
                                                                         acc[mt][nt], 0, 0, 0);
            }
        }

#pragma unroll
        for (int mt = 0; mt < 4; mt++) {
#pragma unroll
            for (int j = 0; j < 4; j++) {
                int o = wbase + mt * 16 + lg * 4 + j;
                float a = sa[mt * 4 + j];
                float s = sh[mt * 4 + j];
#pragma unroll
                for (int nt = 0; nt < 4; nt++) {
                    int n = n0 + nt * 16 + lr;
                    if (n < N_OUT) ob[(size_t)o * N_OUT + n] = a * acc[mt][nt][j] + s;
                }
            }
        }
    }
}

// ---------------------------------------------------------------------------
extern "C" void kernel_launch(void* const* d_in, const int* in_sizes, int n_in,
                              void* d_out, int out_size, void* d_ws, size_t ws_size,
                              hipStream_t stream) {
    const float* x     = (const float*)d_in[0];
    const int*   idx   = (const int*)d_in[1];
    const float* W     = (const float*)d_in[2];
    const float* gamma = (const float*)d_in[4];
    const float* beta  = (const float*)d_in[5];
    float* out = (float*)d_out;

    const size_t xt_bytes = (size_t)B_ * N_IN * C_IN * sizeof(unsigned short);   // 41,945,088
    const size_t g_bytes  = (size_t)B_ * N_OUT * C_IN * sizeof(unsigned short);  // 10,487,808
    const size_t wb_bytes = (size_t)C_OUT * C_IN * sizeof(unsigned short);       // 65,536
    unsigned short* xT = (unsigned short*)d_ws;
    unsigned short* gg = (unsigned short*)((char*)d_ws + xt_bytes);
    unsigned short* Wb = (unsigned short*)((char*)d_ws + xt_bytes + g_bytes);
    float* psum = (float*)((char*)d_ws + xt_bytes + g_bytes + wb_bytes);         // 324*512*4 = 663 KB
    float* ss   = psum + (size_t)NBLK_GS * 2 * C_OUT;
    unsigned int* cnt = (unsigned int*)(ss + 2 * C_OUT);

    k_transpose<<<B_ * NB_I + WCONV_BLKS, 256, 0, stream>>>(x, xT, W, Wb, cnt);
    k_gather<<<B_ * NB_G, 256, 0, stream>>>(xT, idx, gg);
    k_stats_gemm<<<NBLK_GS, 256, 0, stream>>>(gg, Wb, gamma, beta, psum, ss, cnt);
    k_final_gemm<<<B_ * NB_N2, 256, 0, stream>>>(gg, Wb, ss, out);
}

// Round 14
// 84.683 us; speedup vs baseline: 1.7246x; 1.4434x over previous
//
#include <hip/hip_runtime.h>
#include <hip/hip_bf16.h>

#define B_ 4
#define C_IN 128
#define C_OUT 256
#define N_IN 40962
#define N_OUT 10242
#define EPS_ 1e-5f
#define CNT_ ((float)(B_ * N_OUT))

typedef __attribute__((ext_vector_type(8))) short bf16x8;
typedef __attribute__((ext_vector_type(4))) float f32x4;

__device__ __forceinline__ float bf2f(unsigned short u) {
    union { unsigned int i; float f; } c;
    c.i = ((unsigned int)u) << 16;
    return c.f;
}
__device__ __forceinline__ unsigned short f2bf(float f) {
    union { float f; unsigned int i; } c;
    c.f = f;
    unsigned int r = c.i + 0x7FFFu + ((c.i >> 16) & 1u);  // RNE
    return (unsigned short)(r >> 16);
}

// ---------------------------------------------------------------------------
// K1: transpose x[b][k][i] (f32) -> xT[b][i][k] (bf16); trailing blocks do
//     the W f32->bf16 conversion.
// ---------------------------------------------------------------------------
#define IBLK 64
#define NB_I ((N_IN + IBLK - 1) / IBLK)   // 641
#define WCONV_BLKS ((C_OUT * C_IN) / 256) // 128

__global__ __launch_bounds__(256) void k_transpose(const float* __restrict__ x,
                                                   unsigned short* __restrict__ xT,
                                                   const float* __restrict__ W,
                                                   unsigned short* __restrict__ Wb) {
    if (blockIdx.x >= B_ * NB_I) {
        int i = (blockIdx.x - B_ * NB_I) * 256 + threadIdx.x;
        Wb[i] = f2bf(W[i]);
        return;
    }
    __shared__ float tile[IBLK][C_IN + 1];
    int b  = blockIdx.x / NB_I;
    int ib = blockIdx.x % NB_I;
    int i0 = ib * IBLK;
    int t = threadIdx.x;
    int lane = t & 63;
    int q = t >> 6;

    const float* xb = x + (size_t)b * C_IN * N_IN;
    int i = i0 + lane;
    if (i < N_IN) {
#pragma unroll
        for (int p = 0; p < 32; p++) {
            int k = p * 4 + q;
            tile[lane][k] = xb[(size_t)k * N_IN + i];
        }
    }
    __syncthreads();

    unsigned short* xTb = xT + (size_t)b * N_IN * C_IN;
#pragma unroll
    for (int p = 0; p < 16; p++) {
        int il = p * 4 + q;
        int gi = i0 + il;
        if (gi < N_IN) {
            int k2 = lane * 2;
            float a = tile[il][k2];
            float c = tile[il][k2 + 1];
            unsigned int pk = (unsigned int)f2bf(a) | ((unsigned int)f2bf(c) << 16);
            *reinterpret_cast<unsigned int*>(xTb + (size_t)gi * C_IN + k2) = pk;
        }
    }
}

// ---------------------------------------------------------------------------
// K2: gather-mean: g[b][n][k] = mean_j xT[b][idx[7n+j]][k]  (bf16 out)
// 16 threads per n; 2564 blocks for max TLP on the random L3 reads.
// ---------------------------------------------------------------------------
#define GNB 16
#define NB_G ((N_OUT + GNB - 1) / GNB)  // 641

__global__ __launch_bounds__(256) void k_gather(const unsigned short* __restrict__ xT,
                                                const int* __restrict__ idx,
                                                unsigned short* __restrict__ g) {
    int b  = blockIdx.x / NB_G;
    int nb = blockIdx.x % NB_G;
    int t = threadIdx.x;
    int n = nb * GNB + (t >> 4);
    int c = t & 15;
    if (n >= N_OUT) return;

    const unsigned short* xTb = xT + (size_t)b * N_IN * C_IN;
    const int* ip = idx + 7 * n;
    float s[8];
#pragma unroll
    for (int e = 0; e < 8; e++) s[e] = 0.f;
#pragma unroll
    for (int j = 0; j < 7; j++) {
        int id = ip[j];
        bf16x8 v = *reinterpret_cast<const bf16x8*>(xTb + (size_t)id * C_IN + c * 8);
#pragma unroll
        for (int e = 0; e < 8; e++) s[e] += bf2f((unsigned short)v[e]);
    }
    const float inv7 = 1.0f / 7.0f;
    bf16x8 r;
#pragma unroll
    for (int e = 0; e < 8; e++) r[e] = (short)f2bf(s[e] * inv7);
    *reinterpret_cast<bf16x8*>(g + ((size_t)b * N_OUT + n) * C_IN + c * 8) = r;
}

// ---------------------------------------------------------------------------
// GEMM tiling: 128-n tile per block processed as 2x 64-n halves reusing the
// same acc registers (afrag/Wb loaded once per block, epilogue amortized).
// ---------------------------------------------------------------------------
#define NT2 128
#define NB_N2 ((N_OUT + NT2 - 1) / NT2)  // 81
#define NBLK_GS (B_ * NB_N2)             // 324

// K3: GEMM -> per-block per-channel partials of z=Wg (bias folded out; var is
// bias-invariant, mean corrected in k_stats_final).
__global__ __launch_bounds__(256, 2) void k_stats_gemm(const unsigned short* __restrict__ g,
                                                       const unsigned short* __restrict__ Wb,
                                                       float* __restrict__ psum) {
    int bid = blockIdx.x;
    int b  = bid / NB_N2;
    int nb = bid % NB_N2;
    int t = threadIdx.x;
    int w = t >> 6, l = t & 63, lr = l & 15, lg = l >> 4;
    int wbase = w * 64;

    bf16x8 afrag[4][4];
#pragma unroll
    for (int mt = 0; mt < 4; mt++)
#pragma unroll
        for (int ks = 0; ks < 4; ks++)
            afrag[mt][ks] = *reinterpret_cast<const bf16x8*>(
                Wb + (size_t)(wbase + mt * 16 + lr) * C_IN + ks * 32 + lg * 8);

    const unsigned short* gb = g + (size_t)b * N_OUT * C_IN;
    float ps1[16], ps2[16];
#pragma unroll
    for (int m = 0; m < 16; m++) { ps1[m] = 0.f; ps2[m] = 0.f; }

    for (int h = 0; h < 2; h++) {
        int n0 = nb * NT2 + h * 64;
        f32x4 acc[4][4];
#pragma unroll
        for (int mt = 0; mt < 4; mt++)
#pragma unroll
            for (int nt = 0; nt < 4; nt++) acc[mt][nt] = (f32x4)(0.0f);

#pragma unroll
        for (int nt = 0; nt < 4; nt++) {
            int n = n0 + nt * 16 + lr;
            const unsigned short* gr = gb + (size_t)((n < N_OUT) ? n : 0) * C_IN;
#pragma unroll
            for (int ks = 0; ks < 4; ks++) {
                bf16x8 bfr = *reinterpret_cast<const bf16x8*>(gr + ks * 32 + lg * 8);
#pragma unroll
                for (int mt = 0; mt < 4; mt++)
                    acc[mt][nt] = __builtin_amdgcn_mfma_f32_16x16x32_bf16(afrag[mt][ks], bfr,
                                                                         acc[mt][nt], 0, 0, 0);
            }
        }
#pragma unroll
        for (int mt = 0; mt < 4; mt++) {
#pragma unroll
            for (int j = 0; j < 4; j++) {
#pragma unroll
                for (int nt = 0; nt < 4; nt++) {
                    int n = n0 + nt * 16 + lr;
                    if (n < N_OUT) {
                        float v = acc[mt][nt][j];
                        ps1[mt * 4 + j] += v;
                        ps2[mt * 4 + j] += v * v;
                    }
                }
            }
        }
    }

    __shared__ float red[2][C_OUT];
#pragma unroll
    for (int m = 0; m < 16; m++) {
        float a = ps1[m], cc = ps2[m];
#pragma unroll
        for (int d = 1; d < 16; d <<= 1) {
            a  += __shfl_xor(a, d, 64);
            cc += __shfl_xor(cc, d, 64);
        }
        if (lr == 0) {
            int mt = m >> 2, j = m & 3;
            int o = wbase + mt * 16 + lg * 4 + j;
            red[0][o] = a;
            red[1][o] = cc;
        }
    }
    __syncthreads();
    float* pb = psum + (size_t)bid * 2 * C_OUT;
    pb[t] = red[0][t];
    pb[C_OUT + t] = red[1][t];
}

// ---------------------------------------------------------------------------
// K4: merged reduce + finalize. 64 blocks x 4 waves; wave owns channel o.
// ---------------------------------------------------------------------------
__global__ __launch_bounds__(256) void k_stats_final(const float* __restrict__ psum,
                                                     const float* __restrict__ bias,
                                                     const float* __restrict__ gamma,
                                                     const float* __restrict__ beta,
                                                     float* __restrict__ ss) {
    int t = threadIdx.x;
    int w = t >> 6, l = t & 63;
    int o = blockIdx.x * 4 + w;
    float s1 = 0.f, s2 = 0.f;
    for (int i = l; i < NBLK_GS; i += 64) {
        const float* pb = psum + (size_t)i * 2 * C_OUT;
        s1 += pb[o];
        s2 += pb[C_OUT + o];
    }
#pragma unroll
    for (int d = 1; d < 64; d <<= 1) {
        s1 += __shfl_xor(s1, d, 64);
        s2 += __shfl_xor(s2, d, 64);
    }
    if (l == 0) {
        float mz = s1 / CNT_;
        float var = s2 / CNT_ - mz * mz;          // var(y) == var(z)
        float a = gamma[o] * rsqrtf(var + EPS_);
        ss[o] = a;
        // out = a*(z + bias - mean_y) + beta = a*z + (beta - a*mz)
        ss[C_OUT + o] = beta[o] - a * mz;
        (void)bias;
    }
}

// ---------------------------------------------------------------------------
// K5: GEMM (z = Wg) + out = a*z + shift. Same 2-half outer loop.
// ---------------------------------------------------------------------------
__global__ __launch_bounds__(256, 2) void k_final_gemm(const unsigned short* __restrict__ g,
                                                       const unsigned short* __restrict__ Wb,
                                                       const float* __restrict__ ss,
                                                       float* __restrict__ out) {
    int bid = blockIdx.x;
    int b  = bid / NB_N2;
    int nb = bid % NB_N2;
    int t = threadIdx.x;
    int w = t >> 6, l = t & 63, lr = l & 15, lg = l >> 4;
    int wbase = w * 64;

    bf16x8 afrag[4][4];
#pragma unroll
    for (int mt = 0; mt < 4; mt++)
#pragma unroll
        for (int ks = 0; ks < 4; ks++)
            afrag[mt][ks] = *reinterpret_cast<const bf16x8*>(
                Wb + (size_t)(wbase + mt * 16 + lr) * C_IN + ks * 32 + lg * 8);

    float sa[16], sh[16];
#pragma unroll
    for (int mt = 0; mt < 4; mt++)
#pragma unroll
        for (int j = 0; j < 4; j++) {
            int o = wbase + mt * 16 + lg * 4 + j;
            sa[mt * 4 + j] = ss[o];
            sh[mt * 4 + j] = ss[C_OUT + o];
        }

    const unsigned short* gb = g + (size_t)b * N_OUT * C_IN;
    float* ob = out + (size_t)b * C_OUT * N_OUT;

    for (int h = 0; h < 2; h++) {
        int n0 = nb * NT2 + h * 64;
        f32x4 acc[4][4];
#pragma unroll
        for (int mt = 0; mt < 4; mt++)
#pragma unroll
            for (int nt = 0; nt < 4; nt++) acc[mt][nt] = (f32x4)(0.0f);

#pragma unroll
        for (int nt = 0; nt < 4; nt++) {
            int n = n0 + nt * 16 + lr;
            const unsigned short* gr = gb + (size_t)((n < N_OUT) ? n : 0) * C_IN;
#pragma unroll
            for (int ks = 0; ks < 4; ks++) {
                bf16x8 bfr = *reinterpret_cast<const bf16x8*>(gr + ks * 32 + lg * 8);
#pragma unroll
                for (int mt = 0; mt < 4; mt++)
                    acc[mt][nt] = __builtin_amdgcn_mfma_f32_16x16x32_bf16(afrag[mt][ks], bfr,
                                                                         acc[mt][nt], 0, 0, 0);
            }
        }

#pragma unroll
        for (int mt = 0; mt < 4; mt++) {
#pragma unroll
            for (int j = 0; j < 4; j++) {
                int o = wbase + mt * 16 + lg * 4 + j;
                float a = sa[mt * 4 + j];
                float s = sh[mt * 4 + j];
#pragma unroll
                for (int nt = 0; nt < 4; nt++) {
                    int n = n0 + nt * 16 + lr;
                    if (n < N_OUT) ob[(size_t)o * N_OUT + n] = a * acc[mt][nt][j] + s;
                }
            }
        }
    }
}

// ---------------------------------------------------------------------------
extern "C" void kernel_launch(void* const* d_in, const int* in_sizes, int n_in,
                              void* d_out, int out_size, void* d_ws, size_t ws_size,
                              hipStream_t stream) {
    const float* x     = (const float*)d_in[0];
    const int*   idx   = (const int*)d_in[1];
    const float* W     = (const float*)d_in[2];
    const float* bias  = (const float*)d_in[3];
    const float* gamma = (const float*)d_in[4];
    const float* beta  = (const float*)d_in[5];
    float* out = (float*)d_out;

    const size_t xt_bytes = (size_t)B_ * N_IN * C_IN * sizeof(unsigned short);   // 41,945,088
    const size_t g_bytes  = (size_t)B_ * N_OUT * C_IN * sizeof(unsigned short);  // 10,487,808
    const size_t wb_bytes = (size_t)C_OUT * C_IN * sizeof(unsigned short);       // 65,536
    unsigned short* xT = (unsigned short*)d_ws;
    unsigned short* gg = (unsigned short*)((char*)d_ws + xt_bytes);
    unsigned short* Wb = (unsigned short*)((char*)d_ws + xt_bytes + g_bytes);
    float* psum = (float*)((char*)d_ws + xt_bytes + g_bytes + wb_bytes);         // 324*512*4 = 663 KB
    float* ss   = psum + (size_t)NBLK_GS * 2 * C_OUT;

    k_transpose<<<B_ * NB_I + WCONV_BLKS, 256, 0, stream>>>(x, xT, W, Wb);
    k_gather<<<B_ * NB_G, 256, 0, stream>>>(xT, idx, gg);
    k_stats_gemm<<<NBLK_GS, 256, 0, stream>>>(gg, Wb, psum);
    k_stats_final<<<64, 256, 0, stream>>>(psum, bias, gamma, beta, ss);
    k_final_gemm<<<B_ * NB_N2, 256, 0, stream>>>(gg, Wb, ss, out);
}